// Round 14
// baseline (208.250 us; speedup 1.0000x reference)
//
#include <hip/hip_runtime.h>
#include <hip/hip_bf16.h>

// GCN VGAE encoder, 6 dispatches (R13 structure + per-wave DETERMINISTIC scatter):
//   memset ccur | k_bin (512 thr, reg-cached edges, per-wave hist + per-wave
//   scatter bases, LDS counting-sort, 8192-edge chunks) | k_fine_gemm1 (512 thr:
//   per-wave hist -> per-wave scatter; srcidx emit; same-block gemm1) |
//   k_gather<L1, XCD-parity> | k_gemm2 | k_gather<L2 -> out>
// norm factorization: agg[c] = dinv[c]*(sum_e ts[src] + ts[c]) + b, ts = (X@W)*dinv.
// Journal: coop grid.sync ~75us (R11); gather+gemm fusion blows VGPRs to 244 even
// with sequential p-loop (R20/R21 REGRESSED; hipcc unrolls trip-2 loops; dead).
// Degree-perm REGRESSED (R14). Scattered global atomics ~30ns/op (R15).
// R16: ~26.5us per gather dispatch incl ~8-11us dispatch overhead.
// R22: SH=6 FAILED determinism tripwire (cross-block ccur claim order at 611K
//   claims). Coarse claims (196x391) pass reproducibly -- keep.
// R23: fine_gemm1 256->512 threads: 223.2->221.0.
// R24: deterministic per-(block,bucket) slabs REGRESSED 230.6; proved fine phase =
//   LDS-atomic bound (495K conflicts).
// R25: per-wave hist8 in fine_gemm1 (histogram pass): 221.0->219.9.
// R26: same + 512 thr + reg-edges in k_bin: 219.9->206.9 (best). Both binning
//   kernels were LDS-atomic-serialization bound; per-wave privatization = lever.
// R27 (this): privatize the remaining atomic pass -- the order-defining scatter --
//   via in-place per-(wave,bucket) exclusive bases derived from hist8. Emit order
//   becomes wave-major: PROVABLY replay-deterministic + 8x less contention.

constexpr int SH = 7;            // nodes per coarse bucket = 128
constexpr int NB = 1 << SH;      // 128
constexpr int CAP = 6144;        // slab capacity (mean ~4093, ~32 sigma)
constexpr int BMAX = 512;        // max buckets (N <= 65536)
constexpr int CHUNK = 8192;      // edges per block in k_bin
constexpr int EPB = CHUNK / 512; // 16 register-cached edges/thread in k_bin
constexpr int EPT = 12;          // register-cached edges/thread in k_fine (12*512=CAP)

typedef float vf4 __attribute__((ext_vector_type(4)));   // for nontemporal stores

__device__ __forceinline__ void fma4(float4& a, float s, const float4& w) {
    a.x = fmaf(s, w.x, a.x);
    a.y = fmaf(s, w.y, a.y);
    a.z = fmaf(s, w.z, a.z);
    a.w = fmaf(s, w.w, a.w);
}

__device__ __forceinline__ unsigned short f2bf(float f) {  // RNE
    unsigned u = __float_as_uint(f);
    return (unsigned short)((u + 0x7fffu + ((u >> 16) & 1u)) >> 16);
}

__device__ __forceinline__ void acc_bf8(float* a, uint4 v) {
    a[0] += __uint_as_float(v.x << 16);
    a[1] += __uint_as_float(v.x & 0xffff0000u);
    a[2] += __uint_as_float(v.y << 16);
    a[3] += __uint_as_float(v.y & 0xffff0000u);
    a[4] += __uint_as_float(v.z << 16);
    a[5] += __uint_as_float(v.z & 0xffff0000u);
    a[6] += __uint_as_float(v.w << 16);
    a[7] += __uint_as_float(v.w & 0xffff0000u);
}

__device__ __forceinline__ void set_bf8(float* a, uint4 v) {
    a[0] = __uint_as_float(v.x << 16);
    a[1] = __uint_as_float(v.x & 0xffff0000u);
    a[2] = __uint_as_float(v.y << 16);
    a[3] = __uint_as_float(v.y & 0xffff0000u);
    a[4] = __uint_as_float(v.z << 16);
    a[5] = __uint_as_float(v.z & 0xffff0000u);
    a[6] = __uint_as_float(v.w << 16);
    a[7] = __uint_as_float(v.w & 0xffff0000u);
}

// Sum of one (node, quad) stripe of a 32-feat bf16 plane into a[8] (fp32),
// including the self loop. 8-edge unroll for MLP.
__device__ __forceinline__ void gather_core(const int2* __restrict__ range2,
                                            const unsigned short* __restrict__ srcidx,
                                            const uint4* __restrict__ Tp,
                                            int n, int q, float* a) {
    int2 rg = range2[n];
    int k = rg.x, end = rg.y;
    set_bf8(a, Tp[(size_t)n * 4 + q]);       // self loop
    for (; k < end && (k & 3); ++k)          // align to ushort4
        acc_bf8(a, Tp[(size_t)srcidx[k] * 4 + q]);
    for (; k + 8 <= end; k += 8) {
        ushort4 r0 = *reinterpret_cast<const ushort4*>(srcidx + k);
        ushort4 r1 = *reinterpret_cast<const ushort4*>(srcidx + k + 4);
        uint4 v0 = Tp[(size_t)r0.x * 4 + q];
        uint4 v1 = Tp[(size_t)r0.y * 4 + q];
        uint4 v2 = Tp[(size_t)r0.z * 4 + q];
        uint4 v3 = Tp[(size_t)r0.w * 4 + q];
        uint4 v4 = Tp[(size_t)r1.x * 4 + q];
        uint4 v5 = Tp[(size_t)r1.y * 4 + q];
        uint4 v6 = Tp[(size_t)r1.z * 4 + q];
        uint4 v7 = Tp[(size_t)r1.w * 4 + q];
        acc_bf8(a, v0); acc_bf8(a, v1); acc_bf8(a, v2); acc_bf8(a, v3);
        acc_bf8(a, v4); acc_bf8(a, v5); acc_bf8(a, v6); acc_bf8(a, v7);
    }
    if (k + 4 <= end) {
        ushort4 r0 = *reinterpret_cast<const ushort4*>(srcidx + k);
        uint4 v0 = Tp[(size_t)r0.x * 4 + q];
        uint4 v1 = Tp[(size_t)r0.y * 4 + q];
        uint4 v2 = Tp[(size_t)r0.z * 4 + q];
        uint4 v3 = Tp[(size_t)r0.w * 4 + q];
        acc_bf8(a, v0); acc_bf8(a, v1); acc_bf8(a, v2); acc_bf8(a, v3);
        k += 4;
    }
    for (; k < end; ++k)
        acc_bf8(a, Tp[(size_t)srcidx[k] * 4 + q]);
}

// ---------------- k_bin (512 thr, per-wave hist + per-wave scatter) ------------
// LDS counting-sort per 8192-edge chunk:
//   load ebuf[16] (single global read) -> pass1 hist into 8 per-wave copies ->
//   reduce + 512-wide scan -> in-place convert hist8 to per-(wave,bucket)
//   exclusive bases -> ONE ccur atomic per (block,bucket) -> pass2 scatter via
//   per-wave counters (wave-major order: replay-deterministic, 8x less
//   contention) -> contiguous run writes to bucket slabs.
__global__ __launch_bounds__(512) void k_bin(const int* __restrict__ row,
                                             const int* __restrict__ col,
                                             int* __restrict__ ccur,
                                             unsigned* __restrict__ binned,
                                             int E, int B) {
    __shared__ int lbase[BMAX];    // local exclusive base of bucket run
    __shared__ int gbase[BMAX];    // global slab base claimed for this block's run
    __shared__ int hist8[8][BMAX]; // 16KB per-wave hist -> per-wave scatter bases
    __shared__ int segtot[8];
    __shared__ unsigned sorted[CHUNK];   // 32KB
    const int tid = threadIdx.x;
    const int lane = tid & 63, wvi = tid >> 6;
    const int e0 = blockIdx.x * CHUNK;
    const int ecnt = min(E - e0, CHUNK);
    for (int i = tid; i < 8 * BMAX; i += 512) (&hist8[0][0])[i] = 0;
    unsigned ebuf[EPB];
    #pragma unroll
    for (int j = 0; j < EPB; ++j) {
        int e = e0 + tid + j * 512;
        ebuf[j] = (e < E) ? (((unsigned)col[e] << 16) | (unsigned)row[e]) : 0xFFFFFFFFu;
    }
    __syncthreads();
    // pass1: histogram from registers into per-wave copies (order-free)
    int* myh = &hist8[wvi][0];
    #pragma unroll
    for (int j = 0; j < EPB; ++j)
        if (ebuf[j] != 0xFFFFFFFFu) atomicAdd(&myh[ebuf[j] >> (16 + SH)], 1);
    __syncthreads();
    // reduce 8 copies + 512-wide exclusive scan over B (<=512) counts
    int v = 0;
    if (tid < B) {
        #pragma unroll
        for (int w = 0; w < 8; ++w) v += hist8[w][tid];
    }
    int s = v;
    #pragma unroll
    for (int off = 1; off < 64; off <<= 1) {
        int u = __shfl_up(s, off, 64);
        if (lane >= off) s += u;
    }
    if (lane == 63) segtot[wvi] = s;
    __syncthreads();
    int pre = 0;
    for (int j = 0; j < wvi; ++j) pre += segtot[j];
    const int ex = s + pre - v;            // exclusive prefix
    if (tid < B) {
        lbase[tid] = ex;
        // in-place: hist8[w][tid] becomes the w-th wave's scatter base
        int run = ex;
        #pragma unroll
        for (int w = 0; w < 8; ++w) {
            int t = hist8[w][tid];
            hist8[w][tid] = run;
            run += t;
        }
        gbase[tid] = v ? atomicAdd(&ccur[tid], v) : 0;
    }
    __syncthreads();
    // pass2: scatter via per-wave counters (wave-major, deterministic)
    #pragma unroll
    for (int j = 0; j < EPB; ++j) {
        unsigned e = ebuf[j];
        if (e != 0xFFFFFFFFu) {
            int pos = atomicAdd(&myh[e >> (16 + SH)], 1);
            sorted[pos] = e;
        }
    }
    __syncthreads();
    // write out: consecutive i within a run -> consecutive global addresses
    for (int i = tid; i < ecnt; i += 512) {
        unsigned e = sorted[i];
        int b = e >> (16 + SH);
        int g = gbase[b] + (i - lbase[b]);
        if (g < CAP) binned[(size_t)b * CAP + g] = e;
    }
}

// ---------------- k_fine_gemm1 (fused, 512 thr, per-wave hist+scatter) ----------
// One block per 128-node bucket, 8 waves:
//   phase A: register-cache entries (EPT=12, 12*512=CAP, no tails); hist into 8
//            per-wave copies -> reduce -> dinv + ranges (two-wave scan over 128)
//            -> in-place per-(wave,bucket) bases -> per-wave scatter (wave-major,
//            deterministic) into 12KB LDS stage -> coalesced burst.
//   phase B: gemm1 for THIS bucket's 128 nodes, 4 nodes/thread. W1 (32KB) staged
//            early so its latency hides under phase A. T = (X@W1)*dinv -> bf16.
__global__ __launch_bounds__(512) void k_fine_gemm1(
    const unsigned* __restrict__ binned, const int* __restrict__ ccur,
    unsigned short* __restrict__ srcidx, int2* __restrict__ range2,
    float* __restrict__ dinv,
    const float* __restrict__ X, const float* __restrict__ W1,
    unsigned short* __restrict__ Tlo, unsigned short* __restrict__ Thi, int N) {
    __shared__ int hist8[8][NB];                  // 4KB per-wave hist -> bases
    __shared__ float dl[NB];
    __shared__ int w0tot;
    __shared__ uint4 sshv[CAP / 8];               // 12KB ushort stage
    __shared__ float4 Wl[2048];                   // 32KB W1 tile
    unsigned short* ssh = (unsigned short*)sshv;
    const int b = blockIdx.x;
    const int n0 = b << SH;
    const int ebase = b * CAP;
    const int ecnt = min(ccur[b], CAP);
    const int tid = threadIdx.x;
    const int lane = tid & 63, wvi = tid >> 6;
    for (int i = tid; i < 8 * NB; i += 512) (&hist8[0][0])[i] = 0;
    // ---- phase A: fine binning ----
    unsigned ebuf[EPT];
    #pragma unroll
    for (int j = 0; j < EPT; ++j) {
        int i = tid + j * 512;
        ebuf[j] = (i < ecnt) ? binned[ebase + i] : 0xFFFFFFFFu;
    }
    // stage W1 early: global loads issue now, latency retires under phase A
    for (int i = tid; i < 2048; i += 512)
        Wl[i] = reinterpret_cast<const float4*>(W1)[i];
    __syncthreads();
    int* myh = &hist8[wvi][0];
    #pragma unroll
    for (int j = 0; j < EPT; ++j)
        if (ebuf[j] != 0xFFFFFFFFu) atomicAdd(&myh[(ebuf[j] >> 16) & (NB - 1)], 1);
    __syncthreads();
    // reduce 8 copies + exclusive scan over 128 counts (two-wave scan)
    int v = 0;
    if (tid < NB) {
        #pragma unroll
        for (int w = 0; w < 8; ++w) v += hist8[w][tid];
    }
    int s = v;
    #pragma unroll
    for (int off = 1; off < 64; off <<= 1) {
        int u = __shfl_up(s, off, 64);
        if (lane >= off) s += u;
    }
    if (tid == 63) w0tot = s;
    __syncthreads();
    if (tid >= 64 && tid < NB) s += w0tot;
    if (tid < NB) {
        int lb = s - v;                    // LOCAL exclusive base
        int n = n0 + tid;
        float d = rsqrtf((float)v + 1.0f);
        dl[tid] = d;
        if (n < N) {
            range2[n] = make_int2(ebase + lb, ebase + lb + v);
            dinv[n] = d;
        }
        // in-place: hist8[w][tid] becomes the w-th wave's scatter base
        int run = lb;
        #pragma unroll
        for (int w = 0; w < 8; ++w) {
            int t = hist8[w][tid];
            hist8[w][tid] = run;
            run += t;
        }
    }
    __syncthreads();
    // per-wave scatter (wave-major, deterministic)
    #pragma unroll
    for (int j = 0; j < EPT; ++j) {
        unsigned e = ebuf[j];
        if (e != 0xFFFFFFFFu) {
            int pos = atomicAdd(&myh[(e >> 16) & (NB - 1)], 1);
            ssh[pos] = (unsigned short)(e & 0xFFFFu);
        }
    }
    __syncthreads();
    // coalesced srcidx copy-out (round up to 16B; slack stays inside this slab)
    const int n4 = ((ecnt + 7) & ~7) >> 3;
    uint4* gs = reinterpret_cast<uint4*>(srcidx + ebase);
    for (int j = tid; j < n4; j += 512) gs[j] = sshv[j];

    // ---- phase B: gemm1 for nodes [n0, n0+128), 4 nodes/thread ----
    const int fg = tid & 15;           // 16 feature groups x float4 = 64 outputs
    const int ns = tid >> 4;           // 32 node slots
    const float4* Xv = reinterpret_cast<const float4*>(X);
    const float4 z = make_float4(0.f, 0.f, 0.f, 0.f);
    float4 acc[4] = {z, z, z, z};
    int n[4];
    bool vld[4];
    #pragma unroll
    for (int i = 0; i < 4; ++i) { n[i] = n0 + ns + i * 32; vld[i] = n[i] < N; }
    for (int k4 = 0; k4 < 32; ++k4) {
        float4 xv[4];
        #pragma unroll
        for (int i = 0; i < 4; ++i)
            xv[i] = vld[i] ? Xv[(size_t)n[i] * 32 + k4] : z;
        float4 w0 = Wl[(k4 * 4 + 0) * 16 + fg];
        float4 w1 = Wl[(k4 * 4 + 1) * 16 + fg];
        float4 w2 = Wl[(k4 * 4 + 2) * 16 + fg];
        float4 w3 = Wl[(k4 * 4 + 3) * 16 + fg];
        #pragma unroll
        for (int i = 0; i < 4; ++i) {
            fma4(acc[i], xv[i].x, w0); fma4(acc[i], xv[i].y, w1);
            fma4(acc[i], xv[i].z, w2); fma4(acc[i], xv[i].w, w3);
        }
    }
    ushort4* Tp = reinterpret_cast<ushort4*>((fg < 8) ? Tlo : Thi);
    const int j = fg & 7;
    #pragma unroll
    for (int i = 0; i < 4; ++i) {
        if (vld[i]) {
            float d = dl[ns + i * 32];
            ushort4 o;
            o.x = f2bf(acc[i].x * d); o.y = f2bf(acc[i].y * d);
            o.z = f2bf(acc[i].z * d); o.w = f2bf(acc[i].w * d);
            Tp[(size_t)n[i] * 8 + j] = o;
        }
    }
}

// ---------------- k_gemm ----------------
// T planes (bf16 [N][32] x2) = (op(X) @ W) * dinv[n]. 4 nodes/thread, 64-node tiles.
// PIN: X given as two fp32 [N][32] planes (layer 2); else contiguous [N][K].
template <int K, bool RELU, bool TWO_W, bool PIN>
__global__ __launch_bounds__(256) void k_gemm(const float* __restrict__ X,
                                              const float* __restrict__ Xhi,
                                              const float* __restrict__ Wa,
                                              const float* __restrict__ Wb,
                                              const float* __restrict__ dinv,
                                              unsigned short* __restrict__ Tlo,
                                              unsigned short* __restrict__ Thi, int N) {
    __shared__ float4 Wl[K * 16];
    const int tid = threadIdx.x;
    for (int i = tid; i < K * 16; i += 256) {
        if (TWO_W) {
            int k = i >> 4, fgi = i & 15;
            const float* s = (fgi < 8) ? (Wa + k * 32 + fgi * 4)
                                       : (Wb + k * 32 + (fgi - 8) * 4);
            Wl[i] = *reinterpret_cast<const float4*>(s);
        } else {
            Wl[i] = reinterpret_cast<const float4*>(Wa)[i];
        }
    }
    __syncthreads();

    const int fg = tid & 15;
    const int ns = tid >> 4;
    const int nb = blockIdx.x * 64;
    const float4* Xv = reinterpret_cast<const float4*>(X);
    const float4* Xv2 = reinterpret_cast<const float4*>(Xhi);
    const float4 z = make_float4(0.f, 0.f, 0.f, 0.f);
    float4 acc[4] = {z, z, z, z};
    int n[4];
    bool v[4];
    #pragma unroll
    for (int i = 0; i < 4; ++i) { n[i] = nb + ns + i * 16; v[i] = n[i] < N; }

    for (int k4 = 0; k4 < K / 4; ++k4) {
        float4 xv[4];
        #pragma unroll
        for (int i = 0; i < 4; ++i) {
            if (PIN)
                xv[i] = v[i] ? ((k4 < 8) ? Xv[(size_t)n[i] * 8 + k4]
                                         : Xv2[(size_t)n[i] * 8 + (k4 - 8)]) : z;
            else
                xv[i] = v[i] ? Xv[(size_t)n[i] * (K / 4) + k4] : z;
            if (RELU) {
                xv[i].x = fmaxf(xv[i].x, 0.f); xv[i].y = fmaxf(xv[i].y, 0.f);
                xv[i].z = fmaxf(xv[i].z, 0.f); xv[i].w = fmaxf(xv[i].w, 0.f);
            }
        }
        float4 w0 = Wl[(k4 * 4 + 0) * 16 + fg];
        float4 w1 = Wl[(k4 * 4 + 1) * 16 + fg];
        float4 w2 = Wl[(k4 * 4 + 2) * 16 + fg];
        float4 w3 = Wl[(k4 * 4 + 3) * 16 + fg];
        #pragma unroll
        for (int i = 0; i < 4; ++i) {
            fma4(acc[i], xv[i].x, w0); fma4(acc[i], xv[i].y, w1);
            fma4(acc[i], xv[i].z, w2); fma4(acc[i], xv[i].w, w3);
        }
    }
    ushort4* Tp = reinterpret_cast<ushort4*>((fg < 8) ? Tlo : Thi);
    const int j = fg & 7;
    #pragma unroll
    for (int i = 0; i < 4; ++i) {
        if (v[i]) {
            float d = dinv[n[i]];
            ushort4 o;
            o.x = f2bf(acc[i].x * d); o.y = f2bf(acc[i].y * d);
            o.z = f2bf(acc[i].z * d); o.w = f2bf(acc[i].w * d);
            Tp[(size_t)n[i] * 8 + j] = o;
        }
    }
}

// ---------------- k_gather ----------------
// Both planes of one layer in a single dispatch, plane pinned by XCD parity:
// plane = blockIdx&1 (round-robin block->XCD mapping keeps each XCD on one 3.2MB
// plane -> per-XCD L2-resident). Grid = 2 * ceil(N*4/256).
template <bool NT>
__global__ __launch_bounds__(256) void k_gather(
    const int2* __restrict__ range2, const unsigned short* __restrict__ srcidx,
    const uint4* __restrict__ Tlo, const uint4* __restrict__ Thi,
    const float* __restrict__ dinv,
    const float* __restrict__ bias_lo, const float* __restrict__ bias_hi,
    float* __restrict__ dst_lo, float* __restrict__ dst_hi, int N) {
    const int plane = blockIdx.x & 1;
    int idx = (blockIdx.x >> 1) * 256 + threadIdx.x;
    if (idx >= N * 4) return;
    int n = idx >> 2, q = idx & 3;
    float a[8];
    gather_core(range2, srcidx, plane ? Thi : Tlo, n, q, a);
    float d = dinv[n];
    const float* bias = (plane ? bias_hi : bias_lo) + q * 8;
    float* dst = (plane ? dst_hi : dst_lo) + (size_t)n * 32 + q * 8;
    float4 b0 = reinterpret_cast<const float4*>(bias)[0];
    float4 b1 = reinterpret_cast<const float4*>(bias)[1];
    vf4 o0, o1;
    o0.x = fmaf(a[0], d, b0.x); o0.y = fmaf(a[1], d, b0.y);
    o0.z = fmaf(a[2], d, b0.z); o0.w = fmaf(a[3], d, b0.w);
    o1.x = fmaf(a[4], d, b1.x); o1.y = fmaf(a[5], d, b1.y);
    o1.z = fmaf(a[6], d, b1.z); o1.w = fmaf(a[7], d, b1.w);
    if (NT) {
        __builtin_nontemporal_store(o0, reinterpret_cast<vf4*>(dst));
        __builtin_nontemporal_store(o1, reinterpret_cast<vf4*>(dst) + 1);
    } else {
        reinterpret_cast<vf4*>(dst)[0] = o0;
        reinterpret_cast<vf4*>(dst)[1] = o1;
    }
}

extern "C" void kernel_launch(void* const* d_in, const int* in_sizes, int n_in,
                              void* d_out, int out_size, void* d_ws, size_t ws_size,
                              hipStream_t stream) {
    const float* x   = (const float*)d_in[0];
    const int*   ei  = (const int*)d_in[1];
    const float* W1  = (const float*)d_in[2];
    const float* b1  = (const float*)d_in[3];
    const float* Wmu = (const float*)d_in[4];
    const float* bmu = (const float*)d_in[5];
    const float* Wls = (const float*)d_in[6];
    const float* bls = (const float*)d_in[7];

    const int N = in_sizes[0] / 128;
    const int E = in_sizes[1] / 2;
    const int* row = ei;             // sources
    const int* col = ei + E;         // targets
    const int B = (N + NB - 1) >> SH;   // 128-node buckets (<= BMAX)
    const size_t BCAP = (size_t)B * CAP;
    const size_t PL = (size_t)16 * N;   // one bf16 [N][32] plane, in 4B units

    // ws layout (4B units), no overlays:
    // ccur[512] | binned[BCAP] | srcidx ushort[BCAP] (BCAP/2) |
    // t_lo[PL] | t_hi[PL] | dinv[N] | range2 int2[N] | agg_lo f32[32N] | agg_hi f32[32N]
    int* wsi = (int*)d_ws;
    size_t off = 0;
    int* ccur = wsi + off;                                 off += BMAX;
    unsigned* binned = (unsigned*)(wsi + off);             off += BCAP;
    unsigned short* srcidx = (unsigned short*)(wsi + off); off += BCAP / 2;
    unsigned short* t_lo = (unsigned short*)(wsi + off);   off += PL;
    unsigned short* t_hi = (unsigned short*)(wsi + off);   off += PL;
    float* dinv = (float*)(wsi + off);                     off += N;
    int2* range2 = (int2*)(wsi + off);                     off += 2 * (size_t)N;
    float* agg_lo = (float*)(wsi + off);                   off += 32 * (size_t)N;
    float* agg_hi = (float*)(wsi + off);                   off += 32 * (size_t)N;
    float* outp = (float*)d_out;

    const int GG = 2 * ((N * 4 + 255) / 256);   // both planes, parity-split
    const int ntiles = (N + 63) / 64;

    (void)hipMemsetAsync(ccur, 0, BMAX * sizeof(int), stream);
    k_bin<<<(E + CHUNK - 1) / CHUNK, 512, 0, stream>>>(row, col, ccur, binned, E, B);
    k_fine_gemm1<<<B, 512, 0, stream>>>(binned, ccur, srcidx, range2, dinv,
                                        x, W1, t_lo, t_hi, N);
    k_gather<false><<<GG, 256, 0, stream>>>(
        range2, srcidx, (const uint4*)t_lo, (const uint4*)t_hi, dinv,
        b1, b1 + 32, agg_lo, agg_hi, N);

    k_gemm<64, true, true, true><<<ntiles, 256, 0, stream>>>(
        agg_lo, agg_hi, Wmu, Wls, dinv, t_lo, t_hi, N);
    k_gather<true><<<GG, 256, 0, stream>>>(
        range2, srcidx, (const uint4*)t_lo, (const uint4*)t_hi, dinv,
        bmu, bls, outp, outp + 32 * (size_t)N, N);
}

// Round 15
// 206.022 us; speedup vs baseline: 1.0108x; 1.0108x over previous
//
#include <hip/hip_runtime.h>
#include <hip/hip_bf16.h>

// GCN VGAE encoder, 6 dispatches (R13 = session best, 206.9us, FINAL):
//   memset ccur | k_bin (512 thr, reg-cached edges, 8x per-wave hist, LDS
//   counting-sort, 8192-edge chunks) | k_fine_gemm1 (512 thr: 8x per-wave hist ->
//   reduce -> scan; srcidx emit; same-block gemm1) | k_gather<L1, XCD-parity> |
//   k_gemm2 | k_gather<L2 -> out>
// norm factorization: agg[c] = dinv[c]*(sum_e ts[src] + ts[c]) + b, ts = (X@W)*dinv.
// Journal: coop grid.sync ~75us (R11); gather+gemm fusion blows VGPRs to 244 even
// with sequential p-loop (R20/R21 REGRESSED; hipcc unrolls trip-2 loops; dead).
// Degree-perm REGRESSED (R14). Scattered global atomics ~30ns/op (R15).
// R16: ~26.5us per gather dispatch incl ~8-11us dispatch overhead.
// R17: counting-sort k_bin + LDS-staged srcidx: 231.7->223.6.
// R22: SH=6 FAILED determinism tripwire (cross-block ccur claim order at 611K
//   claims). Coarse claims (196x391) pass reproducibly -- keep. Intra-block
//   atomic scatter order passed in every config.
// R23: fine_gemm1 256->512 threads: 223.2->221.0.
// R24: deterministic per-(block,bucket) slabs REGRESSED 230.6; counter row proved
//   fine phase = LDS-atomic bound (495K conflicts).
// R25: per-wave hist8 in fine_gemm1: 221.0->219.9.
// R26: same two levers on k_bin (512 thr + per-wave hist + reg-edges):
//   219.9->206.9 (BEST). Both binning kernels were LDS-atomic-bound.
// R27: per-wave deterministic scatter: NEUTRAL (208.2) -- scatter atomics already
//   latency-hidden at 8-wave occupancy. Reverted. Privatization only pays until
//   occupancy hides the serialization; R26 crossed that line.
// Remaining budget: ~145us kernel work (all latency/request-bound, individually
// treated) + ~60us across 6 dispatch gaps. Gap floor is structural.

constexpr int SH = 7;            // nodes per coarse bucket = 128
constexpr int NB = 1 << SH;      // 128
constexpr int CAP = 6144;        // slab capacity (mean ~4093, ~32 sigma)
constexpr int BMAX = 512;        // max buckets (N <= 65536)
constexpr int CHUNK = 8192;      // edges per block in k_bin
constexpr int EPB = CHUNK / 512; // 16 register-cached edges/thread in k_bin
constexpr int EPT = 12;          // register-cached edges/thread in k_fine (12*512=CAP)

typedef float vf4 __attribute__((ext_vector_type(4)));   // for nontemporal stores

__device__ __forceinline__ void fma4(float4& a, float s, const float4& w) {
    a.x = fmaf(s, w.x, a.x);
    a.y = fmaf(s, w.y, a.y);
    a.z = fmaf(s, w.z, a.z);
    a.w = fmaf(s, w.w, a.w);
}

__device__ __forceinline__ unsigned short f2bf(float f) {  // RNE
    unsigned u = __float_as_uint(f);
    return (unsigned short)((u + 0x7fffu + ((u >> 16) & 1u)) >> 16);
}

__device__ __forceinline__ void acc_bf8(float* a, uint4 v) {
    a[0] += __uint_as_float(v.x << 16);
    a[1] += __uint_as_float(v.x & 0xffff0000u);
    a[2] += __uint_as_float(v.y << 16);
    a[3] += __uint_as_float(v.y & 0xffff0000u);
    a[4] += __uint_as_float(v.z << 16);
    a[5] += __uint_as_float(v.z & 0xffff0000u);
    a[6] += __uint_as_float(v.w << 16);
    a[7] += __uint_as_float(v.w & 0xffff0000u);
}

__device__ __forceinline__ void set_bf8(float* a, uint4 v) {
    a[0] = __uint_as_float(v.x << 16);
    a[1] = __uint_as_float(v.x & 0xffff0000u);
    a[2] = __uint_as_float(v.y << 16);
    a[3] = __uint_as_float(v.y & 0xffff0000u);
    a[4] = __uint_as_float(v.z << 16);
    a[5] = __uint_as_float(v.z & 0xffff0000u);
    a[6] = __uint_as_float(v.w << 16);
    a[7] = __uint_as_float(v.w & 0xffff0000u);
}

// Sum of one (node, quad) stripe of a 32-feat bf16 plane into a[8] (fp32),
// including the self loop. 8-edge unroll for MLP.
__device__ __forceinline__ void gather_core(const int2* __restrict__ range2,
                                            const unsigned short* __restrict__ srcidx,
                                            const uint4* __restrict__ Tp,
                                            int n, int q, float* a) {
    int2 rg = range2[n];
    int k = rg.x, end = rg.y;
    set_bf8(a, Tp[(size_t)n * 4 + q]);       // self loop
    for (; k < end && (k & 3); ++k)          // align to ushort4
        acc_bf8(a, Tp[(size_t)srcidx[k] * 4 + q]);
    for (; k + 8 <= end; k += 8) {
        ushort4 r0 = *reinterpret_cast<const ushort4*>(srcidx + k);
        ushort4 r1 = *reinterpret_cast<const ushort4*>(srcidx + k + 4);
        uint4 v0 = Tp[(size_t)r0.x * 4 + q];
        uint4 v1 = Tp[(size_t)r0.y * 4 + q];
        uint4 v2 = Tp[(size_t)r0.z * 4 + q];
        uint4 v3 = Tp[(size_t)r0.w * 4 + q];
        uint4 v4 = Tp[(size_t)r1.x * 4 + q];
        uint4 v5 = Tp[(size_t)r1.y * 4 + q];
        uint4 v6 = Tp[(size_t)r1.z * 4 + q];
        uint4 v7 = Tp[(size_t)r1.w * 4 + q];
        acc_bf8(a, v0); acc_bf8(a, v1); acc_bf8(a, v2); acc_bf8(a, v3);
        acc_bf8(a, v4); acc_bf8(a, v5); acc_bf8(a, v6); acc_bf8(a, v7);
    }
    if (k + 4 <= end) {
        ushort4 r0 = *reinterpret_cast<const ushort4*>(srcidx + k);
        uint4 v0 = Tp[(size_t)r0.x * 4 + q];
        uint4 v1 = Tp[(size_t)r0.y * 4 + q];
        uint4 v2 = Tp[(size_t)r0.z * 4 + q];
        uint4 v3 = Tp[(size_t)r0.w * 4 + q];
        acc_bf8(a, v0); acc_bf8(a, v1); acc_bf8(a, v2); acc_bf8(a, v3);
        k += 4;
    }
    for (; k < end; ++k)
        acc_bf8(a, Tp[(size_t)srcidx[k] * 4 + q]);
}

// ---------------- k_bin (512 threads, per-wave hist, reg-cached edges) ----------
// LDS counting-sort per 8192-edge chunk:
//   load ebuf[16] (single global read of col/row) -> pass1 hist into 8 per-wave
//   copies (order-free) -> reduce + 512-wide scan -> ONE ccur atomic per
//   (block,bucket) -> pass2 scatter ebuf into LDS sorted order (order-defining,
//   single shared counters) -> contiguous run writes to bucket slabs.
__global__ __launch_bounds__(512) void k_bin(const int* __restrict__ row,
                                             const int* __restrict__ col,
                                             int* __restrict__ ccur,
                                             unsigned* __restrict__ binned,
                                             int E, int B) {
    __shared__ int h[BMAX];        // running local offset (scatter counters)
    __shared__ int lbase[BMAX];    // local exclusive base of bucket run
    __shared__ int gbase[BMAX];    // global slab base claimed for this block's run
    __shared__ int hist8[8][BMAX]; // 16KB per-wave histograms
    __shared__ int segtot[8];
    __shared__ unsigned sorted[CHUNK];   // 32KB
    const int tid = threadIdx.x;
    const int lane = tid & 63, wvi = tid >> 6;
    const int e0 = blockIdx.x * CHUNK;
    const int ecnt = min(E - e0, CHUNK);
    for (int i = tid; i < 8 * BMAX; i += 512) (&hist8[0][0])[i] = 0;
    unsigned ebuf[EPB];
    #pragma unroll
    for (int j = 0; j < EPB; ++j) {
        int e = e0 + tid + j * 512;
        ebuf[j] = (e < E) ? (((unsigned)col[e] << 16) | (unsigned)row[e]) : 0xFFFFFFFFu;
    }
    __syncthreads();
    // pass1: histogram from registers into per-wave copies (order-free)
    int* myh = &hist8[wvi][0];
    #pragma unroll
    for (int j = 0; j < EPB; ++j)
        if (ebuf[j] != 0xFFFFFFFFu) atomicAdd(&myh[ebuf[j] >> (16 + SH)], 1);
    __syncthreads();
    // reduce 8 copies + 512-wide exclusive scan over B (<=512) counts
    int v = 0;
    if (tid < B) {
        #pragma unroll
        for (int w = 0; w < 8; ++w) v += hist8[w][tid];
    }
    int s = v;
    #pragma unroll
    for (int off = 1; off < 64; off <<= 1) {
        int u = __shfl_up(s, off, 64);
        if (lane >= off) s += u;
    }
    if (lane == 63) segtot[wvi] = s;
    __syncthreads();
    int pre = 0;
    for (int j = 0; j < wvi; ++j) pre += segtot[j];
    const int ex = s + pre - v;            // exclusive prefix
    if (tid < B) {
        lbase[tid] = ex; h[tid] = ex;
        gbase[tid] = v ? atomicAdd(&ccur[tid], v) : 0;
    }
    __syncthreads();
    // pass2: scatter registers into LDS sorted-by-bucket order (order-defining)
    #pragma unroll
    for (int j = 0; j < EPB; ++j) {
        unsigned e = ebuf[j];
        if (e != 0xFFFFFFFFu) {
            int pos = atomicAdd(&h[e >> (16 + SH)], 1);
            sorted[pos] = e;
        }
    }
    __syncthreads();
    // write out: consecutive i within a run -> consecutive global addresses
    for (int i = tid; i < ecnt; i += 512) {
        unsigned e = sorted[i];
        int b = e >> (16 + SH);
        int g = gbase[b] + (i - lbase[b]);
        if (g < CAP) binned[(size_t)b * CAP + g] = e;
    }
}

// ---------------- k_fine_gemm1 (fused, 512 threads, per-wave hist) ----------------
// One block per 128-node bucket, 8 waves:
//   phase A: register-cache entries (EPT=12, 12*512=CAP, no tails); HISTOGRAM into
//            8 per-wave copies (order-free, 8x less same-address serialization) ->
//            reduce -> dinv + ranges (two-wave scan over 128); srcidx emit via the
//            single shared running-counter scatter (order-defining, tripwire-proven)
//            into 12KB LDS stage + coalesced burst.
//   phase B: gemm1 for THIS bucket's 128 nodes, 4 nodes/thread. W1 (32KB) staged
//            early so its latency hides under phase A. T = (X@W1)*dinv -> bf16.
__global__ __launch_bounds__(512) void k_fine_gemm1(
    const unsigned* __restrict__ binned, const int* __restrict__ ccur,
    unsigned short* __restrict__ srcidx, int2* __restrict__ range2,
    float* __restrict__ dinv,
    const float* __restrict__ X, const float* __restrict__ W1,
    unsigned short* __restrict__ Tlo, unsigned short* __restrict__ Thi, int N) {
    __shared__ int fine[NB];
    __shared__ int hist8[8][NB];                  // 4KB per-wave histograms
    __shared__ float dl[NB];
    __shared__ int w0tot;
    __shared__ uint4 sshv[CAP / 8];               // 12KB ushort stage
    __shared__ float4 Wl[2048];                   // 32KB W1 tile
    unsigned short* ssh = (unsigned short*)sshv;
    const int b = blockIdx.x;
    const int n0 = b << SH;
    const int ebase = b * CAP;
    const int ecnt = min(ccur[b], CAP);
    const int tid = threadIdx.x;
    const int lane = tid & 63, wvi = tid >> 6;
    for (int i = tid; i < 8 * NB; i += 512) (&hist8[0][0])[i] = 0;
    // ---- phase A: fine binning ----
    unsigned ebuf[EPT];
    #pragma unroll
    for (int j = 0; j < EPT; ++j) {
        int i = tid + j * 512;
        ebuf[j] = (i < ecnt) ? binned[ebase + i] : 0xFFFFFFFFu;
    }
    // stage W1 early: global loads issue now, latency retires under phase A
    for (int i = tid; i < 2048; i += 512)
        Wl[i] = reinterpret_cast<const float4*>(W1)[i];
    __syncthreads();
    int* myh = &hist8[wvi][0];
    #pragma unroll
    for (int j = 0; j < EPT; ++j)
        if (ebuf[j] != 0xFFFFFFFFu) atomicAdd(&myh[(ebuf[j] >> 16) & (NB - 1)], 1);
    __syncthreads();
    // reduce 8 copies + exclusive scan over 128 counts (two-wave scan)
    int v = 0;
    if (tid < NB) {
        #pragma unroll
        for (int w = 0; w < 8; ++w) v += hist8[w][tid];
    }
    int s = v;
    #pragma unroll
    for (int off = 1; off < 64; off <<= 1) {
        int u = __shfl_up(s, off, 64);
        if (lane >= off) s += u;
    }
    if (tid == 63) w0tot = s;
    __syncthreads();
    if (tid >= 64 && tid < NB) s += w0tot;
    if (tid < NB) {
        int lb = s - v;                    // LOCAL exclusive base
        int n = n0 + tid;
        float d = rsqrtf((float)v + 1.0f);
        dl[tid] = d;
        if (n < N) {
            range2[n] = make_int2(ebase + lb, ebase + lb + v);
            dinv[n] = d;
        }
        fine[tid] = lb;                    // shared running counter (order-defining)
    }
    __syncthreads();
    #pragma unroll
    for (int j = 0; j < EPT; ++j) {
        unsigned e = ebuf[j];
        if (e != 0xFFFFFFFFu) {
            int pos = atomicAdd(&fine[(e >> 16) & (NB - 1)], 1);
            ssh[pos] = (unsigned short)(e & 0xFFFFu);
        }
    }
    __syncthreads();
    // coalesced srcidx copy-out (round up to 16B; slack stays inside this slab)
    const int n4 = ((ecnt + 7) & ~7) >> 3;
    uint4* gs = reinterpret_cast<uint4*>(srcidx + ebase);
    for (int j = tid; j < n4; j += 512) gs[j] = sshv[j];

    // ---- phase B: gemm1 for nodes [n0, n0+128), 4 nodes/thread ----
    const int fg = tid & 15;           // 16 feature groups x float4 = 64 outputs
    const int ns = tid >> 4;           // 32 node slots
    const float4* Xv = reinterpret_cast<const float4*>(X);
    const float4 z = make_float4(0.f, 0.f, 0.f, 0.f);
    float4 acc[4] = {z, z, z, z};
    int n[4];
    bool vld[4];
    #pragma unroll
    for (int i = 0; i < 4; ++i) { n[i] = n0 + ns + i * 32; vld[i] = n[i] < N; }
    for (int k4 = 0; k4 < 32; ++k4) {
        float4 xv[4];
        #pragma unroll
        for (int i = 0; i < 4; ++i)
            xv[i] = vld[i] ? Xv[(size_t)n[i] * 32 + k4] : z;
        float4 w0 = Wl[(k4 * 4 + 0) * 16 + fg];
        float4 w1 = Wl[(k4 * 4 + 1) * 16 + fg];
        float4 w2 = Wl[(k4 * 4 + 2) * 16 + fg];
        float4 w3 = Wl[(k4 * 4 + 3) * 16 + fg];
        #pragma unroll
        for (int i = 0; i < 4; ++i) {
            fma4(acc[i], xv[i].x, w0); fma4(acc[i], xv[i].y, w1);
            fma4(acc[i], xv[i].z, w2); fma4(acc[i], xv[i].w, w3);
        }
    }
    ushort4* Tp = reinterpret_cast<ushort4*>((fg < 8) ? Tlo : Thi);
    const int j = fg & 7;
    #pragma unroll
    for (int i = 0; i < 4; ++i) {
        if (vld[i]) {
            float d = dl[ns + i * 32];
            ushort4 o;
            o.x = f2bf(acc[i].x * d); o.y = f2bf(acc[i].y * d);
            o.z = f2bf(acc[i].z * d); o.w = f2bf(acc[i].w * d);
            Tp[(size_t)n[i] * 8 + j] = o;
        }
    }
}

// ---------------- k_gemm ----------------
// T planes (bf16 [N][32] x2) = (op(X) @ W) * dinv[n]. 4 nodes/thread, 64-node tiles.
// PIN: X given as two fp32 [N][32] planes (layer 2); else contiguous [N][K].
template <int K, bool RELU, bool TWO_W, bool PIN>
__global__ __launch_bounds__(256) void k_gemm(const float* __restrict__ X,
                                              const float* __restrict__ Xhi,
                                              const float* __restrict__ Wa,
                                              const float* __restrict__ Wb,
                                              const float* __restrict__ dinv,
                                              unsigned short* __restrict__ Tlo,
                                              unsigned short* __restrict__ Thi, int N) {
    __shared__ float4 Wl[K * 16];
    const int tid = threadIdx.x;
    for (int i = tid; i < K * 16; i += 256) {
        if (TWO_W) {
            int k = i >> 4, fgi = i & 15;
            const float* s = (fgi < 8) ? (Wa + k * 32 + fgi * 4)
                                       : (Wb + k * 32 + (fgi - 8) * 4);
            Wl[i] = *reinterpret_cast<const float4*>(s);
        } else {
            Wl[i] = reinterpret_cast<const float4*>(Wa)[i];
        }
    }
    __syncthreads();

    const int fg = tid & 15;
    const int ns = tid >> 4;
    const int nb = blockIdx.x * 64;
    const float4* Xv = reinterpret_cast<const float4*>(X);
    const float4* Xv2 = reinterpret_cast<const float4*>(Xhi);
    const float4 z = make_float4(0.f, 0.f, 0.f, 0.f);
    float4 acc[4] = {z, z, z, z};
    int n[4];
    bool v[4];
    #pragma unroll
    for (int i = 0; i < 4; ++i) { n[i] = nb + ns + i * 16; v[i] = n[i] < N; }

    for (int k4 = 0; k4 < K / 4; ++k4) {
        float4 xv[4];
        #pragma unroll
        for (int i = 0; i < 4; ++i) {
            if (PIN)
                xv[i] = v[i] ? ((k4 < 8) ? Xv[(size_t)n[i] * 8 + k4]
                                         : Xv2[(size_t)n[i] * 8 + (k4 - 8)]) : z;
            else
                xv[i] = v[i] ? Xv[(size_t)n[i] * (K / 4) + k4] : z;
            if (RELU) {
                xv[i].x = fmaxf(xv[i].x, 0.f); xv[i].y = fmaxf(xv[i].y, 0.f);
                xv[i].z = fmaxf(xv[i].z, 0.f); xv[i].w = fmaxf(xv[i].w, 0.f);
            }
        }
        float4 w0 = Wl[(k4 * 4 + 0) * 16 + fg];
        float4 w1 = Wl[(k4 * 4 + 1) * 16 + fg];
        float4 w2 = Wl[(k4 * 4 + 2) * 16 + fg];
        float4 w3 = Wl[(k4 * 4 + 3) * 16 + fg];
        #pragma unroll
        for (int i = 0; i < 4; ++i) {
            fma4(acc[i], xv[i].x, w0); fma4(acc[i], xv[i].y, w1);
            fma4(acc[i], xv[i].z, w2); fma4(acc[i], xv[i].w, w3);
        }
    }
    ushort4* Tp = reinterpret_cast<ushort4*>((fg < 8) ? Tlo : Thi);
    const int j = fg & 7;
    #pragma unroll
    for (int i = 0; i < 4; ++i) {
        if (v[i]) {
            float d = dinv[n[i]];
            ushort4 o;
            o.x = f2bf(acc[i].x * d); o.y = f2bf(acc[i].y * d);
            o.z = f2bf(acc[i].z * d); o.w = f2bf(acc[i].w * d);
            Tp[(size_t)n[i] * 8 + j] = o;
        }
    }
}

// ---------------- k_gather ----------------
// Both planes of one layer in a single dispatch, plane pinned by XCD parity:
// plane = blockIdx&1 (round-robin block->XCD mapping keeps each XCD on one 3.2MB
// plane -> per-XCD L2-resident). Grid = 2 * ceil(N*4/256).
template <bool NT>
__global__ __launch_bounds__(256) void k_gather(
    const int2* __restrict__ range2, const unsigned short* __restrict__ srcidx,
    const uint4* __restrict__ Tlo, const uint4* __restrict__ Thi,
    const float* __restrict__ dinv,
    const float* __restrict__ bias_lo, const float* __restrict__ bias_hi,
    float* __restrict__ dst_lo, float* __restrict__ dst_hi, int N) {
    const int plane = blockIdx.x & 1;
    int idx = (blockIdx.x >> 1) * 256 + threadIdx.x;
    if (idx >= N * 4) return;
    int n = idx >> 2, q = idx & 3;
    float a[8];
    gather_core(range2, srcidx, plane ? Thi : Tlo, n, q, a);
    float d = dinv[n];
    const float* bias = (plane ? bias_hi : bias_lo) + q * 8;
    float* dst = (plane ? dst_hi : dst_lo) + (size_t)n * 32 + q * 8;
    float4 b0 = reinterpret_cast<const float4*>(bias)[0];
    float4 b1 = reinterpret_cast<const float4*>(bias)[1];
    vf4 o0, o1;
    o0.x = fmaf(a[0], d, b0.x); o0.y = fmaf(a[1], d, b0.y);
    o0.z = fmaf(a[2], d, b0.z); o0.w = fmaf(a[3], d, b0.w);
    o1.x = fmaf(a[4], d, b1.x); o1.y = fmaf(a[5], d, b1.y);
    o1.z = fmaf(a[6], d, b1.z); o1.w = fmaf(a[7], d, b1.w);
    if (NT) {
        __builtin_nontemporal_store(o0, reinterpret_cast<vf4*>(dst));
        __builtin_nontemporal_store(o1, reinterpret_cast<vf4*>(dst) + 1);
    } else {
        reinterpret_cast<vf4*>(dst)[0] = o0;
        reinterpret_cast<vf4*>(dst)[1] = o1;
    }
}

extern "C" void kernel_launch(void* const* d_in, const int* in_sizes, int n_in,
                              void* d_out, int out_size, void* d_ws, size_t ws_size,
                              hipStream_t stream) {
    const float* x   = (const float*)d_in[0];
    const int*   ei  = (const int*)d_in[1];
    const float* W1  = (const float*)d_in[2];
    const float* b1  = (const float*)d_in[3];
    const float* Wmu = (const float*)d_in[4];
    const float* bmu = (const float*)d_in[5];
    const float* Wls = (const float*)d_in[6];
    const float* bls = (const float*)d_in[7];

    const int N = in_sizes[0] / 128;
    const int E = in_sizes[1] / 2;
    const int* row = ei;             // sources
    const int* col = ei + E;         // targets
    const int B = (N + NB - 1) >> SH;   // 128-node buckets (<= BMAX)
    const size_t BCAP = (size_t)B * CAP;
    const size_t PL = (size_t)16 * N;   // one bf16 [N][32] plane, in 4B units

    // ws layout (4B units), no overlays:
    // ccur[512] | binned[BCAP] | srcidx ushort[BCAP] (BCAP/2) |
    // t_lo[PL] | t_hi[PL] | dinv[N] | range2 int2[N] | agg_lo f32[32N] | agg_hi f32[32N]
    int* wsi = (int*)d_ws;
    size_t off = 0;
    int* ccur = wsi + off;                                 off += BMAX;
    unsigned* binned = (unsigned*)(wsi + off);             off += BCAP;
    unsigned short* srcidx = (unsigned short*)(wsi + off); off += BCAP / 2;
    unsigned short* t_lo = (unsigned short*)(wsi + off);   off += PL;
    unsigned short* t_hi = (unsigned short*)(wsi + off);   off += PL;
    float* dinv = (float*)(wsi + off);                     off += N;
    int2* range2 = (int2*)(wsi + off);                     off += 2 * (size_t)N;
    float* agg_lo = (float*)(wsi + off);                   off += 32 * (size_t)N;
    float* agg_hi = (float*)(wsi + off);                   off += 32 * (size_t)N;
    float* outp = (float*)d_out;

    const int GG = 2 * ((N * 4 + 255) / 256);   // both planes, parity-split
    const int ntiles = (N + 63) / 64;

    (void)hipMemsetAsync(ccur, 0, BMAX * sizeof(int), stream);
    k_bin<<<(E + CHUNK - 1) / CHUNK, 512, 0, stream>>>(row, col, ccur, binned, E, B);
    k_fine_gemm1<<<B, 512, 0, stream>>>(binned, ccur, srcidx, range2, dinv,
                                        x, W1, t_lo, t_hi, N);
    k_gather<false><<<GG, 256, 0, stream>>>(
        range2, srcidx, (const uint4*)t_lo, (const uint4*)t_hi, dinv,
        b1, b1 + 32, agg_lo, agg_hi, N);

    k_gemm<64, true, true, true><<<ntiles, 256, 0, stream>>>(
        agg_lo, agg_hi, Wmu, Wls, dinv, t_lo, t_hi, N);
    k_gather<true><<<GG, 256, 0, stream>>>(
        range2, srcidx, (const uint4*)t_lo, (const uint4*)t_hi, dinv,
        bmu, bls, outp, outp + 32 * (size_t)N, N);
}